// Round 1
// 345.717 us; speedup vs baseline: 1.0142x; 1.0142x over previous
//
#include <hip/hip_runtime.h>
#include <hip/hip_bf16.h>
#include <math.h>

#define N_NODES 50000
#define N_EDGES 1600000
#define ET (N_EDGES + N_NODES)   // with self loops
#define IN_C 165
#define HID 256
#define HEADS 8
#define C1 32
#define OUT_C 2
#define NEG_SLOPE 0.2f
#define TROWS 32                           // gemm tile rows
#define XSTR 36                            // padded LDS stride (transposed x tile)
#define GEMM_BLOCKS ((N_NODES + TROWS - 1) / TROWS)  // 1563
#define NPP ((N_NODES + 7) / 8)            // 6250 nodes per dst partition
#define CAPL 96                            // fixed per-node list capacity
                                           // deg ~ 1+Poisson(32); P(>95) ~ 1e-17/node
// interleaved dispatch: groups of 8 blocks (one per XCD); per 16 groups,
// 7 are GEMM and 9 are scatter -> 196 gemm groups (1568 slots >= 1563) and
// 256 scatter groups (256*8 = 2048 scatter blocks, 256 per class).
#define GGRP 196
#define SGRP 256
#define TGRP 452                           // 448 patterned + 4 scatter-only
#define NE4 (N_EDGES / 4)                  // 400000 int4-scan elements

__device__ inline float lrelu(float v) { return v > 0.f ? v : NEG_SLOPE * v; }

// fp32 -> bf16 bits, round-to-nearest-even
__device__ inline unsigned short f32_bf16(float f) {
    unsigned u = __float_as_uint(f);
    return (unsigned short)((u + 0x7FFFu + ((u >> 16) & 1u)) >> 16);
}

__device__ inline float bflo(unsigned u) { return __uint_as_float(u << 16); }
__device__ inline float bfhi(unsigned u) { return __uint_as_float(u & 0xFFFF0000u); }

// ============ gemm1+att block body ============
// 32 rows x 256 cols; thread = 4 rows x 8 cols (32 FMA per k).
// x tile staged TRANSPOSED+padded: xs[k*36 + r] -> conflict-free b128 reads.
// k-loop software-pipelined (distance-1 prefetch of W row + x col).
// Attention dots reduced via in-wave shuffles (no LDS round-trip).
__device__ __forceinline__ void gemm1_att_block(
        int row0, const float* __restrict__ x, const float* __restrict__ W,
        const float* __restrict__ att_src, const float* __restrict__ att_dst,
        unsigned short* __restrict__ h, float* __restrict__ a_src,
        float* __restrict__ a_dst, float* xs) {
    const int tid = threadIdx.x;
    const int nrow = (N_NODES - row0 < TROWS) ? (N_NODES - row0) : TROWS;
    const int lim = nrow * IN_C;
    for (int idx = tid; idx < TROWS * IN_C; idx += 256) {
        int r = idx / IN_C, k = idx - r * IN_C;
        xs[k * XSTR + r] = (idx < lim) ? x[(size_t)row0 * IN_C + idx] : 0.f;
    }
    __syncthreads();
    const int tr = tid >> 5;                  // 0..7: row group (4 rows)
    const int cq = tid & 31;                  // 0..31: col group (8 cols)
    const int c0 = cq * 8;
    float acc[4][8];
    #pragma unroll
    for (int j = 0; j < 4; ++j)
        #pragma unroll
        for (int q = 0; q < 8; ++q) acc[j][q] = 0.f;
    // software-pipelined k-loop: prefetch k+1 while computing k
    float4 xv = *(const float4*)(xs + tr * 4);
    float4 w0 = *(const float4*)(W + c0);
    float4 w1 = *(const float4*)(W + c0 + 4);
    #pragma unroll 3
    for (int k = 0; k < IN_C; ++k) {
        float4 xc = xv, a0 = w0, a1 = w1;
        if (k + 1 < IN_C) {
            xv = *(const float4*)(xs + (k + 1) * XSTR + tr * 4);
            w0 = *(const float4*)(W + (k + 1) * HID + c0);
            w1 = *(const float4*)(W + (k + 1) * HID + c0 + 4);
        }
        #pragma unroll
        for (int j = 0; j < 4; ++j) {
            float xj = (j == 0) ? xc.x : (j == 1) ? xc.y : (j == 2) ? xc.z : xc.w;
            acc[j][0] += xj * a0.x; acc[j][1] += xj * a0.y;
            acc[j][2] += xj * a0.z; acc[j][3] += xj * a0.w;
            acc[j][4] += xj * a1.x; acc[j][5] += xj * a1.y;
            acc[j][6] += xj * a1.z; acc[j][7] += xj * a1.w;
        }
    }
    // store h tile as packed bf16 (8 cols = 16 B = 1 uint4 per row)
    #pragma unroll
    for (int j = 0; j < 4; ++j) {
        int gr = row0 + tr * 4 + j;
        if (gr < N_NODES) {
            unsigned p[4];
            #pragma unroll
            for (int q = 0; q < 4; ++q)
                p[q] = (unsigned)f32_bf16(acc[j][2*q]) |
                       ((unsigned)f32_bf16(acc[j][2*q+1]) << 16);
            *(uint4*)(h + (size_t)gr * HID + c0) = make_uint4(p[0], p[1], p[2], p[3]);
        }
    }
    // fused attention dots: head hd = cq>>2; reduce across the 4 adjacent
    // lanes (cq&3) with shfl_xor 1,2 — no LDS, no barrier.
    {
        const int hd = cq >> 2;
        const float* as = att_src + hd * C1 + (cq & 3) * 8;
        const float* ad = att_dst + hd * C1 + (cq & 3) * 8;
        float av[8], dv[8];
        #pragma unroll
        for (int q = 0; q < 2; ++q) {
            float4 a4 = *(const float4*)(as + q * 4);
            float4 d4 = *(const float4*)(ad + q * 4);
            av[q*4+0]=a4.x; av[q*4+1]=a4.y; av[q*4+2]=a4.z; av[q*4+3]=a4.w;
            dv[q*4+0]=d4.x; dv[q*4+1]=d4.y; dv[q*4+2]=d4.z; dv[q*4+3]=d4.w;
        }
        float ps[4], pd[4];
        #pragma unroll
        for (int j = 0; j < 4; ++j) {
            float s = 0.f, d = 0.f;
            #pragma unroll
            for (int q = 0; q < 8; ++q) {
                s += acc[j][q] * av[q];
                d += acc[j][q] * dv[q];
            }
            ps[j] = s; pd[j] = d;
        }
        #pragma unroll
        for (int off = 1; off <= 2; off <<= 1) {
            #pragma unroll
            for (int j = 0; j < 4; ++j) {
                ps[j] += __shfl_xor(ps[j], off);
                pd[j] += __shfl_xor(pd[j], off);
            }
        }
        if ((cq & 3) == 0) {
            #pragma unroll
            for (int j = 0; j < 4; ++j) {
                int gr = row0 + tr * 4 + j;
                if (gr < N_NODES) {
                    a_src[gr * 8 + hd] = ps[j];
                    a_dst[gr * 8 + hd] = pd[j];
                }
            }
        }
    }
}

// ============ fused: INTERLEAVED gemm || partition-filtered slotted scatter ==
// Dispatch interleaves GEMM and scatter blocks (7:9 per 16 groups of 8) so
// every CU co-hosts VALU-bound GEMM waves and latency-bound scatter waves.
// Scatter class c = blockIdx&7 (round-robin dispatch -> one XCD per class)
// handles only dst in [c*NPP,(c+1)*NPP): atomics hit a 25 KB deg window and
// writes a 1.2 MB csr window -> XCD-local L2, no cross-XCD line ping-pong.
// Real edges scanned as int4 (4x fewer scan loads); self loops inserted
// directly without scanning.
__global__ __launch_bounds__(256) void fusedAB_kernel(
        const float* __restrict__ x, const float* __restrict__ W,
        const float* __restrict__ att_src, const float* __restrict__ att_dst,
        unsigned short* __restrict__ h, float* __restrict__ a_src,
        float* __restrict__ a_dst,
        const int* __restrict__ src, const int* __restrict__ dst,
        int* __restrict__ deg, unsigned short* __restrict__ csr) {
    __shared__ float xs[IN_C * XSTR];         // 23.2 KB
    const int g  = blockIdx.x >> 3;
    const int xc = blockIdx.x & 7;            // XCD id (round-robin dispatch)
    bool is_gemm;
    int rank;
    if (g < 448) {
        const int hi4 = g >> 4, lo4 = g & 15;
        if (lo4 < 7) { is_gemm = true;  rank = hi4 * 7 + lo4; }
        else         { is_gemm = false; rank = hi4 * 9 + lo4 - 7; }
    } else { is_gemm = false; rank = 252 + (g - 448); }

    if (is_gemm) {
        const int gid = rank * 8 + xc;        // 0..1567
        if (gid < GEMM_BLOCKS)
            gemm1_att_block(gid * TROWS, x, W, att_src, att_dst,
                            h, a_src, a_dst, xs);
    } else {
        const int cls = xc;                   // class == XCD
        const int blk = rank;                 // 0..255 within class
        const int lo = cls * NPP;
        const int hi = (lo + NPP < N_NODES) ? lo + NPP : N_NODES;
        const int t = blk * 256 + threadIdx.x;   // 0..65535 within class
        // self loops: no scan needed (src == dst == node)
        if (t < hi - lo) {
            int d = lo + t;
            int slot = atomicAdd(&deg[d], 1);
            csr[(size_t)d * CAPL + slot] = (unsigned short)d;
        }
        // real edges: int4 scan of dst
        const int4* dst4 = (const int4*)dst;
        for (int u = t; u < NE4; u += SGRP * 256) {
            int4 dv = dst4[u];
            #pragma unroll
            for (int j = 0; j < 4; ++j) {
                int d = (j == 0) ? dv.x : (j == 1) ? dv.y : (j == 2) ? dv.z : dv.w;
                if (d >= lo && d < hi) {
                    int slot = atomicAdd(&deg[d], 1);
                    csr[(size_t)d * CAPL + slot] = (unsigned short)src[4 * u + j];
                }
            }
        }
    }
}

// ============ Layer 1 fused: softmax-aggregate(bf16 gather) + bias + ELU
//              + layer-2 GEMM.  One wave per dst node, split into two 32-lane
//              halves that each own one edge (uint4 = 16B/lane gathers):
//              2 edges per memory instruction, 16 edges in flight per wave.
//              Epilogue packs (h2x, h2y, a2s) into one float4/node so agg2
//              gathers ONE line per edge. ==========
__global__ __launch_bounds__(256) void agg1_fused_kernel(
        const int* __restrict__ deg, const unsigned short* __restrict__ csr,
        const float* __restrict__ a_src, const float* __restrict__ a_dst,
        const unsigned short* __restrict__ h1, const float* __restrict__ bias1,
        const float* __restrict__ W2,
        const float* __restrict__ as2, const float* __restrict__ ad2,
        float4* __restrict__ pk, float* __restrict__ a2d) {
    int wid = (blockIdx.x * 256 + threadIdx.x) >> 6;
    int l = threadIdx.x & 63;
    if (wid >= N_NODES) return;
    const int el = l >> 5;                    // edge parity (half-wave)
    const int q  = l & 31;                    // channel octet id
    const int hd = q >> 2;                    // head
    const int ch = q * 8;                     // ushort offset (16 B per lane)
    const unsigned short* lst = csr + (size_t)wid * CAPL;
    const int n = deg[wid];
    const float ad_p = a_dst[wid * 8 + hd];
    float den = 0.f;
    float acc[8];
    #pragma unroll
    for (int k = 0; k < 8; ++k) acc[k] = 0.f;
    int i = 0;
    // main batch: 8 steps x 2 edges = 16 edges per iteration
    for (; i + 16 <= n; i += 16) {
        int s[8];
        #pragma unroll
        for (int j = 0; j < 8; ++j) s[j] = lst[i + 2 * j + el];
        uint4 v[8];
        #pragma unroll
        for (int j = 0; j < 8; ++j)
            v[j] = *(const uint4*)(h1 + (size_t)s[j] * HID + ch);
        float w[8];
        #pragma unroll
        for (int j = 0; j < 8; ++j)
            w[j] = __expf(lrelu(a_src[s[j] * 8 + hd] + ad_p));
        #pragma unroll
        for (int j = 0; j < 8; ++j) {
            den += w[j];
            acc[0] += w[j] * bflo(v[j].x); acc[1] += w[j] * bfhi(v[j].x);
            acc[2] += w[j] * bflo(v[j].y); acc[3] += w[j] * bfhi(v[j].y);
            acc[4] += w[j] * bflo(v[j].z); acc[5] += w[j] * bfhi(v[j].z);
            acc[6] += w[j] * bflo(v[j].w); acc[7] += w[j] * bfhi(v[j].w);
        }
    }
    // mid batch: 4 steps x 2 edges = 8 edges
    if (i + 8 <= n) {
        int s[4];
        #pragma unroll
        for (int j = 0; j < 4; ++j) s[j] = lst[i + 2 * j + el];
        uint4 v[4];
        #pragma unroll
        for (int j = 0; j < 4; ++j)
            v[j] = *(const uint4*)(h1 + (size_t)s[j] * HID + ch);
        float w[4];
        #pragma unroll
        for (int j = 0; j < 4; ++j)
            w[j] = __expf(lrelu(a_src[s[j] * 8 + hd] + ad_p));
        #pragma unroll
        for (int j = 0; j < 4; ++j) {
            den += w[j];
            acc[0] += w[j] * bflo(v[j].x); acc[1] += w[j] * bfhi(v[j].x);
            acc[2] += w[j] * bflo(v[j].y); acc[3] += w[j] * bfhi(v[j].y);
            acc[4] += w[j] * bflo(v[j].z); acc[5] += w[j] * bfhi(v[j].z);
            acc[6] += w[j] * bflo(v[j].w); acc[7] += w[j] * bfhi(v[j].w);
        }
        i += 8;
    }
    // tail singles
    for (; i < n; i += 2) {
        int e = i + el;
        if (e < n) {
            int s = lst[e];
            uint4 v = *(const uint4*)(h1 + (size_t)s * HID + ch);
            float w = __expf(lrelu(a_src[s * 8 + hd] + ad_p));
            den += w;
            acc[0] += w * bflo(v.x); acc[1] += w * bfhi(v.x);
            acc[2] += w * bflo(v.y); acc[3] += w * bfhi(v.y);
            acc[4] += w * bflo(v.z); acc[5] += w * bfhi(v.z);
            acc[6] += w * bflo(v.w); acc[7] += w * bfhi(v.w);
        }
    }
    // combine the two edge-parity halves
    den += __shfl_xor(den, 32);
    #pragma unroll
    for (int k = 0; k < 8; ++k) acc[k] += __shfl_xor(acc[k], 32);

    const float inv = 1.f / den;
    float4 bva = *(const float4*)(bias1 + ch);
    float4 bvb = *(const float4*)(bias1 + ch + 4);
    float o[8];
    o[0] = acc[0] * inv + bva.x; o[1] = acc[1] * inv + bva.y;
    o[2] = acc[2] * inv + bva.z; o[3] = acc[3] * inv + bva.w;
    o[4] = acc[4] * inv + bvb.x; o[5] = acc[5] * inv + bvb.y;
    o[6] = acc[6] * inv + bvb.z; o[7] = acc[7] * inv + bvb.w;
    #pragma unroll
    for (int k = 0; k < 8; ++k) o[k] = o[k] > 0.f ? o[k] : expm1f(o[k]);
    // ---- fused layer-2 GEMM: lane owns hx channels ch..ch+7 ----
    const float* wv = W2 + q * 16;            // rows ch..ch+7, 2 cols, row-major
    float4 w0 = *(const float4*)(wv);
    float4 w1 = *(const float4*)(wv + 4);
    float4 w2 = *(const float4*)(wv + 8);
    float4 w3 = *(const float4*)(wv + 12);
    float p0 = o[0]*w0.x + o[1]*w0.z + o[2]*w1.x + o[3]*w1.z
             + o[4]*w2.x + o[5]*w2.z + o[6]*w3.x + o[7]*w3.z;
    float p1 = o[0]*w0.y + o[1]*w0.w + o[2]*w1.y + o[3]*w1.w
             + o[4]*w2.y + o[5]*w2.w + o[6]*w3.y + o[7]*w3.w;
    #pragma unroll
    for (int off = 16; off; off >>= 1) {      // reduce within the 32-lane half
        p0 += __shfl_xor(p0, off);
        p1 += __shfl_xor(p1, off);
    }
    if (l == 0) {
        pk[wid] = make_float4(p0, p1, p0 * as2[0] + p1 * as2[1], 0.f);
        a2d[wid] = p0 * ad2[0] + p1 * ad2[1];
    }
}

// ============ Layer 2 fused: 16 lanes per node (deg~33), 4 nodes/wave ========
// One float4 gather per edge: (h2x, h2y, a2s, -).  2x unrolled for MLP.
__global__ __launch_bounds__(256) void agg2_fused_kernel(
        const int* __restrict__ deg, const unsigned short* __restrict__ csr,
        const float4* __restrict__ pk, const float* __restrict__ a2d,
        const float* __restrict__ b2, float* __restrict__ out) {
    int t = blockIdx.x * 256 + threadIdx.x;
    int node = t >> 4;
    int l = t & 15;
    if (node >= N_NODES) return;
    const unsigned short* lst = csr + (size_t)node * CAPL;
    const int n = deg[node];
    const float adv = a2d[node];
    float sm = 0.f, acc0 = 0.f, acc1 = 0.f;
    int i = l;
    for (; i + 16 < n; i += 32) {
        int s0 = lst[i], s1 = lst[i + 16];
        float4 p0 = pk[s0], p1 = pk[s1];
        float w0 = __expf(lrelu(p0.z + adv));
        float w1 = __expf(lrelu(p1.z + adv));
        sm += w0 + w1;
        acc0 += w0 * p0.x + w1 * p1.x;
        acc1 += w0 * p0.y + w1 * p1.y;
    }
    for (; i < n; i += 16) {
        int s = lst[i];
        float4 pv = pk[s];
        float w = __expf(lrelu(pv.z + adv));
        sm += w;
        acc0 += w * pv.x;
        acc1 += w * pv.y;
    }
    #pragma unroll
    for (int off = 8; off; off >>= 1) {       // xor stays within the 16-group
        sm   += __shfl_xor(sm, off);
        acc0 += __shfl_xor(acc0, off);
        acc1 += __shfl_xor(acc1, off);
    }
    if (l == 0) {
        *(float2*)(out + node * 2) =
            make_float2(acc0 / sm + b2[0], acc1 / sm + b2[1]);
    }
}

extern "C" void kernel_launch(void* const* d_in, const int* in_sizes, int n_in,
                              void* d_out, int out_size, void* d_ws, size_t ws_size,
                              hipStream_t stream) {
    (void)in_sizes; (void)n_in; (void)out_size; (void)ws_size;
    const float* x        = (const float*)d_in[0];
    const int*   ei       = (const int*)d_in[1];
    const float* W1       = (const float*)d_in[2];
    const float* att_src1 = (const float*)d_in[3];
    const float* att_dst1 = (const float*)d_in[4];
    const float* b1       = (const float*)d_in[5];
    const float* W2       = (const float*)d_in[6];
    const float* att_src2 = (const float*)d_in[7];
    const float* att_dst2 = (const float*)d_in[8];
    const float* b2       = (const float*)d_in[9];
    float* out = (float*)d_out;

    const int* src = ei;
    const int* dst = ei + N_EDGES;

    // ---- workspace carve-up (bytes) ----
    char* ws = (char*)d_ws;
    size_t off = 0;
    unsigned short* h1 = (unsigned short*)(ws + off);
    off += (size_t)N_NODES * HID * 2;                                      // 25.6 MB bf16
    float* a_src1 = (float*)(ws + off); off += (size_t)N_NODES * HEADS * 4;
    float* a_dst1 = (float*)(ws + off); off += (size_t)N_NODES * HEADS * 4;
    float4* pk = (float4*)(ws + off); off += (size_t)N_NODES * 16;         // 800 KB
    float* a2d = (float*)(ws + off); off += (size_t)N_NODES * 4;
    int* deg    = (int*)(ws + off); off += (size_t)N_NODES * 4;
    unsigned short* csr = (unsigned short*)(ws + off);
    off += (size_t)N_NODES * CAPL * 2;                                     // 9.6 MB

    hipMemsetAsync(deg, 0, (size_t)N_NODES * 4, stream);

    const int NW = (N_NODES * 64 + 255) / 256;        // wave-per-node grids

    // ---- interleaved full gemm || partition-filtered slotted scatter ----
    fusedAB_kernel<<<TGRP * 8, 256, 0, stream>>>(
        x, W1, att_src1, att_dst1, h1, a_src1, a_dst1, src, dst, deg, csr);

    // ---- layer 1 aggregate + ELU + layer 2 GEMM (fused) ----
    agg1_fused_kernel<<<NW, 256, 0, stream>>>(
        deg, csr, a_src1, a_dst1, h1, b1, W2, att_src2, att_dst2, pk, a2d);

    // ---- layer 2 aggregate ----
    agg2_fused_kernel<<<(N_NODES * 16 + 255) / 256, 256, 0, stream>>>(
        deg, csr, pk, a2d, b2, out);
}

// Round 2
// 339.685 us; speedup vs baseline: 1.0322x; 1.0178x over previous
//
#include <hip/hip_runtime.h>
#include <hip/hip_bf16.h>
#include <math.h>

#define N_NODES 50000
#define N_EDGES 1600000
#define ET (N_EDGES + N_NODES)   // with self loops
#define IN_C 165
#define HID 256
#define HEADS 8
#define C1 32
#define OUT_C 2
#define NEG_SLOPE 0.2f
#define TROWS 32                           // gemm tile rows
#define XSTR 36                            // padded LDS stride (transposed x tile)
#define GEMM_BLOCKS ((N_NODES + TROWS - 1) / TROWS)  // 1563
#define SCB 2048                           // scatter blocks (8 classes x 256)
#define SGRP 256                           // scatter blocks per class
#define NPP ((N_NODES + 7) / 8)            // 6250 nodes per dst partition
#define CAPL 96                            // fixed per-node list capacity
                                           // deg ~ 1+Poisson(32); P(>95) ~ 1e-17/node
#define NE4 (N_EDGES / 4)                  // 400000 int4-scan elements
#define CK 8                               // W k-chunk (rows per LDS stage)
#define NCH 21                             // ceil(165/8); last chunk = 5 rows

__device__ inline float lrelu(float v) { return v > 0.f ? v : NEG_SLOPE * v; }

// fp32 -> bf16 bits, round-to-nearest-even
__device__ inline unsigned short f32_bf16(float f) {
    unsigned u = __float_as_uint(f);
    return (unsigned short)((u + 0x7FFFu + ((u >> 16) & 1u)) >> 16);
}

__device__ inline float bflo(unsigned u) { return __uint_as_float(u << 16); }
__device__ inline float bfhi(unsigned u) { return __uint_as_float(u & 0xFFFF0000u); }

// ============ gemm1+att block body ============
// 32 rows x 256 cols; thread = 4 rows x 8 cols (32 FMA per k).
// x tile staged TRANSPOSED+padded: xs[k*36 + r] -> conflict-free b128 reads.
// W staged through LDS in double-buffered 8-k chunks (R2): the old direct-L1
// path demanded 128 B/cyc/CU from L1 (waves duplicate W cols; R_t=4 ->
// 512/R_t) vs ~64 supply -> VALU capped ~35%. LDS supplies 256 B/cyc.
// Even/odd granule split per k-row (even float4 -> slot u, odd -> slot u+32)
// makes both reads phase-optimal (512 B unique, 2-way broadcast free).
// Chunk c+1 prefetched to regs before computing chunk c (T14 split).
__device__ __forceinline__ void gemm1_att_block(
        int row0, const float* __restrict__ x, const float* __restrict__ W,
        const float* __restrict__ att_src, const float* __restrict__ att_dst,
        unsigned short* __restrict__ h, float* __restrict__ a_src,
        float* __restrict__ a_dst, float* xs, float* wb) {
    const int tid = threadIdx.x;
    const int nrow = (N_NODES - row0 < TROWS) ? (N_NODES - row0) : TROWS;
    const int lim = nrow * IN_C;
    for (int idx = tid; idx < TROWS * IN_C; idx += 256) {
        int r = idx / IN_C, k = idx - r * IN_C;
        xs[k * XSTR + r] = (idx < lim) ? x[(size_t)row0 * IN_C + idx] : 0.f;
    }
    // stage W chunk 0: thread t loads row (t>>5), cols 8*(t&31).. (32 B)
    const int u  = tid & 31;                  // granule-pair id within row
    const int kr = tid >> 5;                  // k-row within chunk (0..7)
    {
        const float* ws = W + (size_t)kr * HID + u * 8;
        float4 pa = *(const float4*)(ws);
        float4 pb = *(const float4*)(ws + 4);
        *(float4*)(wb + (kr * 64 + u) * 4)      = pa;   // even granule
        *(float4*)(wb + (kr * 64 + u + 32) * 4) = pb;   // odd granule
    }
    __syncthreads();

    const int tr = tid >> 5;                  // 0..7: row group (4 rows)
    const int cq = tid & 31;                  // 0..31: col group (8 cols)
    const int c0 = cq * 8;
    float acc[4][8];
    #pragma unroll
    for (int j = 0; j < 4; ++j)
        #pragma unroll
        for (int q = 0; q < 8; ++q) acc[j][q] = 0.f;

    #pragma unroll 2
    for (int c = 0; c < NCH - 1; ++c) {
        // prefetch chunk c+1 into regs (source rows clamped for the tail)
        int krow = (c + 1) * CK + kr;
        if (krow > IN_C - 1) krow = IN_C - 1;
        const float* ws = W + (size_t)krow * HID + u * 8;
        float4 pa = *(const float4*)(ws);
        float4 pb = *(const float4*)(ws + 4);
        // compute chunk c from buf[c&1]
        const float* wcur = wb + (c & 1) * (CK * 256);
        const int k0 = c * CK;
        #pragma unroll
        for (int kk = 0; kk < CK; ++kk) {
            float4 xc = *(const float4*)(xs + (k0 + kk) * XSTR + tr * 4);
            float4 a0 = *(const float4*)(wcur + (kk * 64 + cq) * 4);
            float4 a1 = *(const float4*)(wcur + (kk * 64 + cq + 32) * 4);
            #pragma unroll
            for (int j = 0; j < 4; ++j) {
                float xj = (j == 0) ? xc.x : (j == 1) ? xc.y : (j == 2) ? xc.z : xc.w;
                acc[j][0] += xj * a0.x; acc[j][1] += xj * a0.y;
                acc[j][2] += xj * a0.z; acc[j][3] += xj * a0.w;
                acc[j][4] += xj * a1.x; acc[j][5] += xj * a1.y;
                acc[j][6] += xj * a1.z; acc[j][7] += xj * a1.w;
            }
        }
        // land prefetched chunk into the other buffer
        float* wnxt = wb + ((c + 1) & 1) * (CK * 256);
        *(float4*)(wnxt + (kr * 64 + u) * 4)      = pa;
        *(float4*)(wnxt + (kr * 64 + u + 32) * 4) = pb;
        __syncthreads();
    }
    // tail chunk (c = 20, k = 160..164, 5 rows) in buf[0]
    {
        const float* wcur = wb + ((NCH - 1) & 1) * (CK * 256);
        const int k0 = (NCH - 1) * CK;
        #pragma unroll
        for (int kk = 0; kk < IN_C - (NCH - 1) * CK; ++kk) {
            float4 xc = *(const float4*)(xs + (k0 + kk) * XSTR + tr * 4);
            float4 a0 = *(const float4*)(wcur + (kk * 64 + cq) * 4);
            float4 a1 = *(const float4*)(wcur + (kk * 64 + cq + 32) * 4);
            #pragma unroll
            for (int j = 0; j < 4; ++j) {
                float xj = (j == 0) ? xc.x : (j == 1) ? xc.y : (j == 2) ? xc.z : xc.w;
                acc[j][0] += xj * a0.x; acc[j][1] += xj * a0.y;
                acc[j][2] += xj * a0.z; acc[j][3] += xj * a0.w;
                acc[j][4] += xj * a1.x; acc[j][5] += xj * a1.y;
                acc[j][6] += xj * a1.z; acc[j][7] += xj * a1.w;
            }
        }
    }
    // store h tile as packed bf16 (8 cols = 16 B = 1 uint4 per row)
    #pragma unroll
    for (int j = 0; j < 4; ++j) {
        int gr = row0 + tr * 4 + j;
        if (gr < N_NODES) {
            unsigned p[4];
            #pragma unroll
            for (int q = 0; q < 4; ++q)
                p[q] = (unsigned)f32_bf16(acc[j][2*q]) |
                       ((unsigned)f32_bf16(acc[j][2*q+1]) << 16);
            *(uint4*)(h + (size_t)gr * HID + c0) = make_uint4(p[0], p[1], p[2], p[3]);
        }
    }
    // fused attention dots: head hd = cq>>2; reduce across the 4 adjacent
    // lanes (cq&3) with shfl_xor 1,2 — no LDS, no barrier.
    {
        const int hd = cq >> 2;
        const float* as = att_src + hd * C1 + (cq & 3) * 8;
        const float* ad = att_dst + hd * C1 + (cq & 3) * 8;
        float av[8], dv[8];
        #pragma unroll
        for (int q = 0; q < 2; ++q) {
            float4 a4 = *(const float4*)(as + q * 4);
            float4 d4 = *(const float4*)(ad + q * 4);
            av[q*4+0]=a4.x; av[q*4+1]=a4.y; av[q*4+2]=a4.z; av[q*4+3]=a4.w;
            dv[q*4+0]=d4.x; dv[q*4+1]=d4.y; dv[q*4+2]=d4.z; dv[q*4+3]=d4.w;
        }
        float ps[4], pd[4];
        #pragma unroll
        for (int j = 0; j < 4; ++j) {
            float s = 0.f, d = 0.f;
            #pragma unroll
            for (int q = 0; q < 8; ++q) {
                s += acc[j][q] * av[q];
                d += acc[j][q] * dv[q];
            }
            ps[j] = s; pd[j] = d;
        }
        #pragma unroll
        for (int off = 1; off <= 2; off <<= 1) {
            #pragma unroll
            for (int j = 0; j < 4; ++j) {
                ps[j] += __shfl_xor(ps[j], off);
                pd[j] += __shfl_xor(pd[j], off);
            }
        }
        if ((cq & 3) == 0) {
            #pragma unroll
            for (int j = 0; j < 4; ++j) {
                int gr = row0 + tr * 4 + j;
                if (gr < N_NODES) {
                    a_src[gr * 8 + hd] = ps[j];
                    a_dst[gr * 8 + hd] = pd[j];
                }
            }
        }
    }
}

// ============ fused: FULL gemm || partition-filtered slotted scatter =========
// Scatter class c = sb&7 (round-robin dispatch -> one XCD per class)
// handles only dst in [c*NPP,(c+1)*NPP): atomics hit a 25 KB deg window and
// writes a 1.2 MB csr window -> XCD-local L2, no cross-XCD line ping-pong.
// Real edges scanned as int4 (4x fewer scan loads); self loops inserted
// directly without scanning.
__global__ __launch_bounds__(256) void fusedAB_kernel(
        const float* __restrict__ x, const float* __restrict__ W,
        const float* __restrict__ att_src, const float* __restrict__ att_dst,
        unsigned short* __restrict__ h, float* __restrict__ a_src,
        float* __restrict__ a_dst,
        const int* __restrict__ src, const int* __restrict__ dst,
        int* __restrict__ deg, unsigned short* __restrict__ csr) {
    __shared__ float xs[IN_C * XSTR];         // 23.2 KB
    __shared__ float wlds[2 * CK * 256];      // 16 KB W double-buffer
    if (blockIdx.x < GEMM_BLOCKS) {
        gemm1_att_block(blockIdx.x * TROWS, x, W, att_src, att_dst,
                        h, a_src, a_dst, xs, wlds);
    } else {
        const int sb  = blockIdx.x - GEMM_BLOCKS;   // 0..SCB-1
        const int cls = sb & 7;
        const int blk = sb >> 3;                    // 0..255 within class
        const int lo = cls * NPP;
        const int hi = (lo + NPP < N_NODES) ? lo + NPP : N_NODES;
        const int t = blk * 256 + threadIdx.x;      // 0..65535 within class
        // self loops: no scan needed (src == dst == node)
        if (t < hi - lo) {
            int d = lo + t;
            int slot = atomicAdd(&deg[d], 1);
            csr[(size_t)d * CAPL + slot] = (unsigned short)d;
        }
        // real edges: int4 scan of dst
        const int4* dst4 = (const int4*)dst;
        for (int uu = t; uu < NE4; uu += SGRP * 256) {
            int4 dv = dst4[uu];
            #pragma unroll
            for (int j = 0; j < 4; ++j) {
                int d = (j == 0) ? dv.x : (j == 1) ? dv.y : (j == 2) ? dv.z : dv.w;
                if (d >= lo && d < hi) {
                    int slot = atomicAdd(&deg[d], 1);
                    csr[(size_t)d * CAPL + slot] = (unsigned short)src[4 * uu + j];
                }
            }
        }
    }
}

// ============ Layer 1 fused: softmax-aggregate(bf16 gather) + bias + ELU
//              + layer-2 GEMM.  One wave per dst node, split into two 32-lane
//              halves that each own one edge (uint4 = 16B/lane gathers):
//              2 edges per memory instruction, 16 edges in flight per wave.
//              Epilogue packs (h2x, h2y, a2s) into one float4/node so agg2
//              gathers ONE line per edge. ==========
__global__ __launch_bounds__(256) void agg1_fused_kernel(
        const int* __restrict__ deg, const unsigned short* __restrict__ csr,
        const float* __restrict__ a_src, const float* __restrict__ a_dst,
        const unsigned short* __restrict__ h1, const float* __restrict__ bias1,
        const float* __restrict__ W2,
        const float* __restrict__ as2, const float* __restrict__ ad2,
        float4* __restrict__ pk, float* __restrict__ a2d) {
    int wid = (blockIdx.x * 256 + threadIdx.x) >> 6;
    int l = threadIdx.x & 63;
    if (wid >= N_NODES) return;
    const int el = l >> 5;                    // edge parity (half-wave)
    const int q  = l & 31;                    // channel octet id
    const int hd = q >> 2;                    // head
    const int ch = q * 8;                     // ushort offset (16 B per lane)
    const unsigned short* lst = csr + (size_t)wid * CAPL;
    const int n = deg[wid];
    const float ad_p = a_dst[wid * 8 + hd];
    float den = 0.f;
    float acc[8];
    #pragma unroll
    for (int k = 0; k < 8; ++k) acc[k] = 0.f;
    int i = 0;
    // main batch: 8 steps x 2 edges = 16 edges per iteration
    for (; i + 16 <= n; i += 16) {
        int s[8];
        #pragma unroll
        for (int j = 0; j < 8; ++j) s[j] = lst[i + 2 * j + el];
        uint4 v[8];
        #pragma unroll
        for (int j = 0; j < 8; ++j)
            v[j] = *(const uint4*)(h1 + (size_t)s[j] * HID + ch);
        float w[8];
        #pragma unroll
        for (int j = 0; j < 8; ++j)
            w[j] = __expf(lrelu(a_src[s[j] * 8 + hd] + ad_p));
        #pragma unroll
        for (int j = 0; j < 8; ++j) {
            den += w[j];
            acc[0] += w[j] * bflo(v[j].x); acc[1] += w[j] * bfhi(v[j].x);
            acc[2] += w[j] * bflo(v[j].y); acc[3] += w[j] * bfhi(v[j].y);
            acc[4] += w[j] * bflo(v[j].z); acc[5] += w[j] * bfhi(v[j].z);
            acc[6] += w[j] * bflo(v[j].w); acc[7] += w[j] * bfhi(v[j].w);
        }
    }
    // mid batch: 4 steps x 2 edges = 8 edges
    if (i + 8 <= n) {
        int s[4];
        #pragma unroll
        for (int j = 0; j < 4; ++j) s[j] = lst[i + 2 * j + el];
        uint4 v[4];
        #pragma unroll
        for (int j = 0; j < 4; ++j)
            v[j] = *(const uint4*)(h1 + (size_t)s[j] * HID + ch);
        float w[4];
        #pragma unroll
        for (int j = 0; j < 4; ++j)
            w[j] = __expf(lrelu(a_src[s[j] * 8 + hd] + ad_p));
        #pragma unroll
        for (int j = 0; j < 4; ++j) {
            den += w[j];
            acc[0] += w[j] * bflo(v[j].x); acc[1] += w[j] * bfhi(v[j].x);
            acc[2] += w[j] * bflo(v[j].y); acc[3] += w[j] * bfhi(v[j].y);
            acc[4] += w[j] * bflo(v[j].z); acc[5] += w[j] * bfhi(v[j].z);
            acc[6] += w[j] * bflo(v[j].w); acc[7] += w[j] * bfhi(v[j].w);
        }
        i += 8;
    }
    // tail singles
    for (; i < n; i += 2) {
        int e = i + el;
        if (e < n) {
            int s = lst[e];
            uint4 v = *(const uint4*)(h1 + (size_t)s * HID + ch);
            float w = __expf(lrelu(a_src[s * 8 + hd] + ad_p));
            den += w;
            acc[0] += w * bflo(v.x); acc[1] += w * bfhi(v.x);
            acc[2] += w * bflo(v.y); acc[3] += w * bfhi(v.y);
            acc[4] += w * bflo(v.z); acc[5] += w * bfhi(v.z);
            acc[6] += w * bflo(v.w); acc[7] += w * bfhi(v.w);
        }
    }
    // combine the two edge-parity halves
    den += __shfl_xor(den, 32);
    #pragma unroll
    for (int k = 0; k < 8; ++k) acc[k] += __shfl_xor(acc[k], 32);

    const float inv = 1.f / den;
    float4 bva = *(const float4*)(bias1 + ch);
    float4 bvb = *(const float4*)(bias1 + ch + 4);
    float o[8];
    o[0] = acc[0] * inv + bva.x; o[1] = acc[1] * inv + bva.y;
    o[2] = acc[2] * inv + bva.z; o[3] = acc[3] * inv + bva.w;
    o[4] = acc[4] * inv + bvb.x; o[5] = acc[5] * inv + bvb.y;
    o[6] = acc[6] * inv + bvb.z; o[7] = acc[7] * inv + bvb.w;
    #pragma unroll
    for (int k = 0; k < 8; ++k) o[k] = o[k] > 0.f ? o[k] : expm1f(o[k]);
    // ---- fused layer-2 GEMM: lane owns hx channels ch..ch+7 ----
    const float* wv = W2 + q * 16;            // rows ch..ch+7, 2 cols, row-major
    float4 w0 = *(const float4*)(wv);
    float4 w1 = *(const float4*)(wv + 4);
    float4 w2 = *(const float4*)(wv + 8);
    float4 w3 = *(const float4*)(wv + 12);
    float p0 = o[0]*w0.x + o[1]*w0.z + o[2]*w1.x + o[3]*w1.z
             + o[4]*w2.x + o[5]*w2.z + o[6]*w3.x + o[7]*w3.z;
    float p1 = o[0]*w0.y + o[1]*w0.w + o[2]*w1.y + o[3]*w1.w
             + o[4]*w2.y + o[5]*w2.w + o[6]*w3.y + o[7]*w3.w;
    #pragma unroll
    for (int off = 16; off; off >>= 1) {      // reduce within the 32-lane half
        p0 += __shfl_xor(p0, off);
        p1 += __shfl_xor(p1, off);
    }
    if (l == 0) {
        pk[wid] = make_float4(p0, p1, p0 * as2[0] + p1 * as2[1], 0.f);
        a2d[wid] = p0 * ad2[0] + p1 * ad2[1];
    }
}

// ============ Layer 2 fused: 16 lanes per node (deg~33), 4 nodes/wave ========
// One float4 gather per edge: (h2x, h2y, a2s, -).  2x unrolled for MLP.
__global__ __launch_bounds__(256) void agg2_fused_kernel(
        const int* __restrict__ deg, const unsigned short* __restrict__ csr,
        const float4* __restrict__ pk, const float* __restrict__ a2d,
        const float* __restrict__ b2, float* __restrict__ out) {
    int t = blockIdx.x * 256 + threadIdx.x;
    int node = t >> 4;
    int l = t & 15;
    if (node >= N_NODES) return;
    const unsigned short* lst = csr + (size_t)node * CAPL;
    const int n = deg[node];
    const float adv = a2d[node];
    float sm = 0.f, acc0 = 0.f, acc1 = 0.f;
    int i = l;
    for (; i + 16 < n; i += 32) {
        int s0 = lst[i], s1 = lst[i + 16];
        float4 p0 = pk[s0], p1 = pk[s1];
        float w0 = __expf(lrelu(p0.z + adv));
        float w1 = __expf(lrelu(p1.z + adv));
        sm += w0 + w1;
        acc0 += w0 * p0.x + w1 * p1.x;
        acc1 += w0 * p0.y + w1 * p1.y;
    }
    for (; i < n; i += 16) {
        int s = lst[i];
        float4 pv = pk[s];
        float w = __expf(lrelu(pv.z + adv));
        sm += w;
        acc0 += w * pv.x;
        acc1 += w * pv.y;
    }
    #pragma unroll
    for (int off = 8; off; off >>= 1) {       // xor stays within the 16-group
        sm   += __shfl_xor(sm, off);
        acc0 += __shfl_xor(acc0, off);
        acc1 += __shfl_xor(acc1, off);
    }
    if (l == 0) {
        *(float2*)(out + node * 2) =
            make_float2(acc0 / sm + b2[0], acc1 / sm + b2[1]);
    }
}

extern "C" void kernel_launch(void* const* d_in, const int* in_sizes, int n_in,
                              void* d_out, int out_size, void* d_ws, size_t ws_size,
                              hipStream_t stream) {
    (void)in_sizes; (void)n_in; (void)out_size; (void)ws_size;
    const float* x        = (const float*)d_in[0];
    const int*   ei       = (const int*)d_in[1];
    const float* W1       = (const float*)d_in[2];
    const float* att_src1 = (const float*)d_in[3];
    const float* att_dst1 = (const float*)d_in[4];
    const float* b1       = (const float*)d_in[5];
    const float* W2       = (const float*)d_in[6];
    const float* att_src2 = (const float*)d_in[7];
    const float* att_dst2 = (const float*)d_in[8];
    const float* b2       = (const float*)d_in[9];
    float* out = (float*)d_out;

    const int* src = ei;
    const int* dst = ei + N_EDGES;

    // ---- workspace carve-up (bytes) ----
    char* ws = (char*)d_ws;
    size_t off = 0;
    unsigned short* h1 = (unsigned short*)(ws + off);
    off += (size_t)N_NODES * HID * 2;                                      // 25.6 MB bf16
    float* a_src1 = (float*)(ws + off); off += (size_t)N_NODES * HEADS * 4;
    float* a_dst1 = (float*)(ws + off); off += (size_t)N_NODES * HEADS * 4;
    float4* pk = (float4*)(ws + off); off += (size_t)N_NODES * 16;         // 800 KB
    float* a2d = (float*)(ws + off); off += (size_t)N_NODES * 4;
    int* deg    = (int*)(ws + off); off += (size_t)N_NODES * 4;
    unsigned short* csr = (unsigned short*)(ws + off);
    off += (size_t)N_NODES * CAPL * 2;                                     // 9.6 MB

    hipMemsetAsync(deg, 0, (size_t)N_NODES * 4, stream);

    const int NW = (N_NODES * 64 + 255) / 256;        // wave-per-node grids

    // ---- full gemm || partition-filtered slotted scatter ----
    fusedAB_kernel<<<GEMM_BLOCKS + SCB, 256, 0, stream>>>(
        x, W1, att_src1, att_dst1, h1, a_src1, a_dst1, src, dst, deg, csr);

    // ---- layer 1 aggregate + ELU + layer 2 GEMM (fused) ----
    agg1_fused_kernel<<<NW, 256, 0, stream>>>(
        deg, csr, a_src1, a_dst1, h1, b1, W2, att_src2, att_dst2, pk, a2d);

    // ---- layer 2 aggregate ----
    agg2_fused_kernel<<<(N_NODES * 16 + 255) / 256, 256, 0, stream>>>(
        deg, csr, pk, a2d, b2, out);
}